// Round 21
// baseline (71.827 us; speedup 1.0000x reference)
//
#include <hip/hip_runtime.h>
#include <math.h>

#define L_ 8192
#define EMB_ 256
#define HID_ 64

typedef __attribute__((ext_vector_type(8))) short bf16x8;
typedef __attribute__((ext_vector_type(4))) float f32x4;
typedef __attribute__((ext_vector_type(4))) int i32x4;

// workspace layout (floats)
#define OFF_TFB  0           // ushort[512][2][64][8]  synthesis B-frags, hi only
#define OFF_TLB  262144      // ushort[256][4][64][8]  analysis B-frags, hi only
#define OFF_AFB  524288      // ushort[32][6][4][64][16] A-frags (hi+lo)
#define OFF_XFRP 917504      // float[32][128][2048] per-Kseg DFT partials, transposed (32 MB)
#define OFF_B2   9306112     // float[32*64]
#define OFF_PHI  9308160     // float[32*32*4]
#define OFF_GB   9312256     // float2[32*64]
#define OFF_WT   9316352     // float[2][32][64][64][2] transposed mix weights (2 MB)
#define OFF_XT   9840640     // dword[128][4096][16]: (bf16 x[2j,ch], bf16 x[2j+1,ch]) (33.5 MB)

__device__ inline int pkbf(float a, float b) {
    int r;
    asm volatile("v_cvt_pk_bf16_f32 %0, %1, %2" : "=v"(r) : "v"(a), "v"(b));
    return r;
}
__device__ inline bf16x8 asbf(i32x4 v) { union { i32x4 i; bf16x8 h; } u; u.i = v; return u.h; }
#define MFMA(A,B,C) __builtin_amdgcn_mfma_f32_16x16x32_bf16((A),(B),(C),0,0,0)

__device__ inline ushort f2bf(float v) {
    unsigned b = __float_as_uint(v);
    return (ushort)((b + 0x7FFFu + ((b >> 16) & 1u)) >> 16);
}
__device__ inline float bf2f(ushort h) { return __uint_as_float(((unsigned)h) << 16); }
// hardware trig: input in REVOLUTIONS; arg r/8192 is already reduced
__device__ inline float hwsin(float rev) { float r; asm("v_sin_f32 %0, %1" : "=v"(r) : "v"(rev)); return r; }
__device__ inline float hwcos(float rev) { float r; asm("v_cos_f32 %0, %1" : "=v"(r) : "v"(rev)); return r; }
// byte-select from {hi,lo}: idx 0-3 = lo bytes, 4-7 = hi bytes
__device__ inline unsigned permb(unsigned hi, unsigned lo, unsigned sel) {
    unsigned r;
    asm("v_perm_b32 %0, %1, %2, %3" : "=v"(r) : "v"(hi), "v"(lo), "v"(sel));
    return r;
}

// merged init: trig (0..4095) + phi (4096..4111) + mlp (4112..4143) + W-transpose (4144..4271)
__global__ __launch_bounds__(256) void k_init(ushort* __restrict__ TLB, ushort* __restrict__ TFB,
        const float* __restrict__ emb,
        const float* __restrict__ Arp, const float* __restrict__ Aip,
        const float* __restrict__ Arn, const float* __restrict__ Ain, float* __restrict__ phi,
        const float* __restrict__ w1, const float* __restrict__ b1,
        const float* __restrict__ w2, const float* __restrict__ b2, float* __restrict__ gb,
        const float* __restrict__ wpos, const float* __restrict__ wneg, float* __restrict__ WT) {
    int bid = blockIdx.x;
    if (bid < 4096) {
        int idx = bid * 256 + threadIdx.x;   // 0..1048575
        int f, l; ushort* dst;
        if (idx < 524288) {                  // TLB: [kstep 256][ct 4][lane 64][e 8]
            int u = idx;
            int e = u & 7, lane = (u >> 3) & 63, ct = (u >> 9) & 3, kstep = u >> 11;
            l = kstep * 32 + ((lane >> 4) << 3) + e;
            f = ct * 16 + (lane & 15);
            dst = TLB + u;
        } else {                             // TFB: [lt 512][ts 2][lane 64][e 8]
            int u = idx - 524288;
            int e = u & 7, lane = (u >> 3) & 63, ts = (u >> 9) & 1, lt = u >> 10;
            l = lt * 16 + (lane & 15);
            f = ts * 32 + ((lane >> 4) << 3) + e;
            dst = TFB + u;
        }
        int fr = f & 31; bool sinp = (f & 32) != 0;
        int r = (fr * l) & (L_ - 1);
        float rev = (float)r * (1.0f / (float)L_);
        float v = sinp ? hwsin(rev) : hwcos(rev);
        *dst = f2bf(v);
    } else if (bid < 4112) {
        int tid = (bid - 4096) * 256 + threadIdx.x;   // (b*32+mm)*4+cmp
        int b = tid >> 7;
        int mm = (tid >> 2) & 31;
        int cmp = tid & 3;
        const float* A = (cmp == 0) ? Arp : (cmp == 1) ? Aip : (cmp == 2) ? Arn : Ain;
        const float4* e4 = (const float4*)(emb + b * EMB_);
        const float4* a4 = (const float4*)(A + mm * EMB_);
        float acc = 0.f;
        for (int q = 0; q < EMB_ / 4; ++q) {
            float4 ev = e4[q], av = a4[q];
            acc += ev.x * av.x + ev.y * av.y + ev.z * av.z + ev.w * av.w;
        }
        phi[tid] = acc;
    } else if (bid < 4144) {
        __shared__ float h[HID_];
        int b = bid - 4112, t = threadIdx.x;
        if (t < HID_) {
            const float4* e4 = (const float4*)(emb + b * EMB_);
            const float4* w4 = (const float4*)(w1 + t * EMB_);
            float acc = b1[t];
            for (int q = 0; q < EMB_ / 4; ++q) {
                float4 ev = e4[q], wv = w4[q];
                acc += ev.x * wv.x + ev.y * wv.y + ev.z * wv.z + ev.w * wv.w;
            }
            h[t] = acc / (1.f + expf(-acc));
        }
        __syncthreads();
        if (t < 128) {
            float g = b2[t];
            const float4* h4 = (const float4*)h;
            const float4* w4 = (const float4*)(w2 + t * HID_);
            for (int q = 0; q < HID_ / 4; ++q) {
                float4 hv = h4[q], wv = w4[q];
                g += hv.x * wv.x + hv.y * wv.y + hv.z * wv.z + hv.w * wv.w;
            }
            if (t < 64) gb[(b * 64 + t) * 2 + 0] = 1.f + g;
            else        gb[(b * 64 + (t - 64)) * 2 + 1] = g;
        }
    } else {
        // W transpose: W[i][o][mm][ri] -> WT[side][mm][i][o][ri]
        int t = bid - 4144;              // 0..127
        int side = t >> 6, i = t & 63;
        const float* W = side ? wneg : wpos;
        const float* src = W + (size_t)i * 4096;
        int tid = threadIdx.x;
        #pragma unroll
        for (int j = 0; j < 8; ++j) {
            int u = tid + 256 * j;       // 0..2047 float2 units: mm = u>>6, o = u&63
            int mm = u >> 6, o = u & 63;
            float2 v = *(const float2*)(src + o * 64 + mm * 2);
            *(float2*)(WT + ((size_t)(side * 32 + mm)) * 8192 + i * 128 + o * 2) = v;
        }
    }
}

// single-bf16 MFMA DFT, ONE WAVE per block (no cross-wave coupling).
// grid 4096 = stripe(128: 16 rows) x lseg(32: K=256); each wave owns its full tile.
__global__ __launch_bounds__(64, 4) void k_dft(const float* __restrict__ x,
        const ushort* __restrict__ TLB, float* __restrict__ xfrp, unsigned* __restrict__ XT2) {
    __shared__ float sBuf[16][132];          // 8.4 KB: uint staging view + float transpose view
    unsigned* sU = (unsigned*)&sBuf[0][0];   // staged as [16][68] uints
    int stripe = blockIdx.x >> 5;
    int lseg = blockIdx.x & 31;
    int lane = threadIdx.x;
    int r0 = stripe * 16;
    int kb0 = lseg * 256;

    f32x4 acc[8];
    #pragma unroll
    for (int i = 0; i < 8; ++i) acc[i] = (f32x4){0.f, 0.f, 0.f, 0.f};

    const i32x4* tb = (const i32x4*)TLB;
    int tbase = (kb0 >> 5) * 256 + lane;    // i32x4 index; +256 per kstep, +64 per ct
    const i32x4 SM = {(int)0x80000000, (int)0x80000000, (int)0x80000000, (int)0x80000000};

    int lrow2 = lane >> 5;                  // 0/1: which of the row-pair this lane loads
    int lcol = (lane & 31) * 4;             // column (floats) within 128-chunk
    int jw = (lane & 31) * 2;               // dword j for ds_write
    int frow = lane & 15;                   // fragment row
    int fj = (lane >> 4) * 4;               // fragment dword base (kgrp*4)

    #pragma unroll
    for (int c = 0; c < 2; ++c) {
        int cbase = kb0 + c * 128;
        // coalesced global load: 8 instrs, 2 rows (2 segments) each
        float4 f0 = *(const float4*)(x + (size_t)(r0 + 0  + lrow2) * L_ + cbase + lcol);
        float4 f1 = *(const float4*)(x + (size_t)(r0 + 2  + lrow2) * L_ + cbase + lcol);
        float4 f2 = *(const float4*)(x + (size_t)(r0 + 4  + lrow2) * L_ + cbase + lcol);
        float4 f3 = *(const float4*)(x + (size_t)(r0 + 6  + lrow2) * L_ + cbase + lcol);
        float4 f4 = *(const float4*)(x + (size_t)(r0 + 8  + lrow2) * L_ + cbase + lcol);
        float4 f5 = *(const float4*)(x + (size_t)(r0 + 10 + lrow2) * L_ + cbase + lcol);
        float4 f6 = *(const float4*)(x + (size_t)(r0 + 12 + lrow2) * L_ + cbase + lcol);
        float4 f7 = *(const float4*)(x + (size_t)(r0 + 14 + lrow2) * L_ + cbase + lcol);
        __syncthreads();                    // 1-wave barrier: protects sBuf reuse (cheap)
        #define STG(i, fv)                                                   \
            {                                                                \
                unsigned d0 = (unsigned)pkbf(fv.x, fv.y);                    \
                unsigned d1 = (unsigned)pkbf(fv.z, fv.w);                    \
                sU[(i * 2 + lrow2) * 68 + jw]     = d0;                      \
                sU[(i * 2 + lrow2) * 68 + jw + 1] = d1;                      \
            }
        STG(0, f0) STG(1, f1) STG(2, f2) STG(3, f3)
        STG(4, f4) STG(5, f5) STG(6, f6) STG(7, f7)
        #undef STG
        __syncthreads();
        // MFMA: A-frag = one ds_read_b128 per ks
        #pragma unroll
        for (int ks = 0; ks < 4; ++ks) {
            i32x4 av = *(const i32x4*)&sU[frow * 68 + ks * 16 + fj];
            bf16x8 AH = asbf(av);
            int ti = tbase + (c * 4 + ks) * 256;
            i32x4 t0 = tb[ti], t1 = tb[ti + 64], t2 = tb[ti + 128], t3 = tb[ti + 192];
            acc[0] = MFMA(AH, asbf(t0), acc[0]); acc[4] = MFMA(AH, asbf(t0 ^ SM), acc[4]);
            acc[1] = MFMA(AH, asbf(t1), acc[1]); acc[5] = MFMA(AH, asbf(t1 ^ SM), acc[5]);
            acc[2] = MFMA(AH, asbf(t2), acc[2]); acc[6] = MFMA(AH, asbf(t2 ^ SM), acc[6]);
            acc[3] = MFMA(AH, asbf(t3), acc[3]); acc[7] = MFMA(AH, asbf(t3 ^ SM), acc[7]);
        }
        // XT2 coalesced store pass: 4 x 1KB dwordx4 stores from transposed LDS read
        {
            unsigned* xtc = XT2 + ((size_t)stripe * 4096 + (cbase >> 1)) * 16;
            int ch4 = (lane & 3) * 4;
            #pragma unroll
            for (int q = 0; q < 4; ++q) {
                int j = q * 16 + (lane >> 2);
                uint4 v;
                v.x = sU[(ch4 + 0) * 68 + j];
                v.y = sU[(ch4 + 1) * 68 + j];
                v.z = sU[(ch4 + 2) * 68 + j];
                v.w = sU[(ch4 + 3) * 68 + j];
                *(uint4*)(xtc + (size_t)(q * 256 + lane * 4)) = v;
            }
        }
    }
    // XFRP epilogue: transpose acc via sBuf (float view), coalesced-ish stores
    __syncthreads();
    int crow = (lane >> 4) << 2;
    int ccol = lane & 15;
    #pragma unroll
    for (int ct = 0; ct < 8; ++ct)
        #pragma unroll
        for (int r = 0; r < 4; ++r)
            sBuf[crow + r][ct * 16 + ccol] = acc[ct][r];
    __syncthreads();
    #pragma unroll
    for (int i = 0; i < 32; ++i) {
        int e = lane + 64 * i;              // 0..2047
        int rr = e & 15, cc = e >> 4;
        xfrp[((size_t)(lseg * 128 + cc)) * 2048 + r0 + rr] = sBuf[rr][cc];
    }
}

// mode mixing -> AFB fragments directly.
// blocks 0..255: [mm 32][side 2][bh 4] spectral rows (8 b each); blocks 256..287: Ax fold + bias2
__global__ __launch_bounds__(256) void k_mix(const float* __restrict__ xfrt,
        const float* __restrict__ WT,
        const float* __restrict__ phi, const float* __restrict__ lw,
        const float* __restrict__ lb, const float* __restrict__ gb,
        ushort* __restrict__ afb, float* __restrict__ bias2) {
    int bi = blockIdx.x;
    int tid = threadIdx.x;
    if (bi >= 256) {                 // Ax fold + bias2
        int b = bi - 256;
        ushort* dst = afb + (size_t)b * 24576;
        #pragma unroll
        for (int j = 0; j < 16; ++j) {
            int u = tid + 256 * j;   // 0..4095 : [ks2 2][mt 4][lane 64][e 8]
            int e = u & 7, lane = (u >> 3) & 63, mt = (u >> 9) & 3, ks2 = u >> 11;
            int c = mt * 16 + (lane & 15);
            int kk = ((lane >> 4) << 3) + e;
            float v = lw[c * 64 + ks2 * 32 + kk] * gb[(b * 64 + c) * 2];
            ushort hi = f2bf(v);
            int base = (((4 + ks2) * 4 + mt) * 64 + lane) * 16;
            dst[base + e] = hi;
            dst[base + 8 + e] = f2bf(v - bf2f(hi));
        }
        if (tid < 64) {
            float g1 = gb[(b * 64 + tid) * 2], be = gb[(b * 64 + tid) * 2 + 1];
            bias2[b * 64 + tid] = lb[tid] * g1 + be;
        }
        return;
    }
    __shared__ float sW[64][64][2];     // [i][o][re/im]
    __shared__ float sXr[8][64], sXi[8][64];   // [b_local][i]
    int bh = bi & 3, side = (bi >> 2) & 1, mm = bi >> 3;
    int slot = side ? (31 - mm) : mm;
    int colR = side ? (64 + slot) : mm;
    int colI = side ? (96 + slot) : (32 + mm);

    // stage transposed W tile: coalesced float4
    {
        const float4* wt = (const float4*)(WT + ((size_t)(side * 32 + mm)) * 8192);
        float* sWlin = &sW[0][0][0];
        #pragma unroll
        for (int j = 0; j < 8; ++j) {
            int u = tid + 256 * j;
            *(float4*)&sWlin[u * 4] = wt[u];
        }
    }
    {   // stage 8 b x 64 i sums via float2 per thread; sum 32 slabs
        const float2* pR = (const float2*)(xfrt + (size_t)colR * 2048 + bh * 512);
        const float2* pI = (const float2*)(xfrt + (size_t)colI * 2048 + bh * 512);
        float2 aR = {0, 0}, aI = {0, 0};
        #pragma unroll
        for (int s = 0; s < 32; ++s) {
            float2 vR = pR[(size_t)s * 131072 + tid];
            float2 vI = pI[(size_t)s * 131072 + tid];
            aR.x += vR.x; aR.y += vR.y;
            aI.x += vI.x; aI.y += vI.y;
        }
        if (!side) { aI.x = -aI.x; aI.y = -aI.y; }
        *(float2*)&sXr[tid >> 5][(tid & 31) * 2] = aR;
        *(float2*)&sXi[tid >> 5][(tid & 31) * 2] = aI;
    }
    __syncthreads();

    int o = tid & 63, bg = tid >> 6;
    const float invL = 1.f / (float)L_;
    float fac = (slot == 0) ? invL : 2.f * invL;
    int comp = side ? 2 : 0;
    int e = slot & 7, kgrp = slot >> 3;
    int mt = o >> 4, lane = kgrp * 16 + (o & 15);
    #pragma unroll
    for (int bl = 0; bl < 2; ++bl) {
        int b_local = bg * 2 + bl;
        int b = bh * 8 + b_local;
        float sre = 0.f, sim = 0.f;
        #pragma unroll 16
        for (int i = 0; i < 64; ++i) {
            float wr = sW[i][o][0], wi = sW[i][o][1];
            float xr = sXr[b_local][i], xi = sXi[b_local][i];
            sre += xr * wr - xi * wi;
            sim += xr * wi + xi * wr;
        }
        const float* ph = &phi[(b * 32 + mm) * 4 + (side ? 2 : 0)];
        float phr = ph[0], phim = ph[1];
        float Pre = sre * phr - sim * phim;
        float Pim = sre * phim + sim * phr;
        float a = fac * Pre;
        float bcoef = (slot == 0) ? 0.f : (side ? 2.f * invL * Pim : -2.f * invL * Pim);
        ushort* dst = afb + (size_t)b * 24576;
        ushort hiA = f2bf(a);
        int baseA = ((comp * 4 + mt) * 64 + lane) * 16;
        dst[baseA + e] = hiA;
        dst[baseA + 8 + e] = f2bf(a - bf2f(hiA));
        ushort hiB = f2bf(bcoef);
        int baseB = (((comp + 1) * 4 + mt) * 64 + lane) * 16;
        dst[baseB + e] = hiB;
        dst[baseB + 8 + e] = f2bf(bcoef - bf2f(hiB));
    }
}

// MFMA epilogue GEMM: out[b][c][l] = silu( sum_k A[k][c] * B[k][l] + bias2[c] ),
// B = [T(64); (-1)^l T(64); x[b](64)]; x read from XT2 dword-pairs + v_perm parity extract.
#define TPART(ts)                                                                        \
    {                                                                                    \
        i32x4 bh_[2];                                                                    \
        _Pragma("unroll")                                                                \
        for (int nj = 0; nj < 2; ++nj)                                                   \
            bh_[nj] = tb[((lt0 + nj) * 2 + (ts)) * 64 + lane];                           \
        _Pragma("unroll")                                                                \
        for (int mt = 0; mt < 4; ++mt) {                                                 \
            i32x4 ah0 = ab[(((ts) * 4 + mt) * 64 + lane) * 2];                           \
            i32x4 ah1 = ab[(((2 + (ts)) * 4 + mt) * 64 + lane) * 2];                     \
            bf16x8 AH0 = asbf(ah0), AH1 = asbf(ah1);                                     \
            _Pragma("unroll")                                                            \
            for (int nj = 0; nj < 2; ++nj) {                                             \
                acc[mt][nj] = MFMA(AH0, asbf(bh_[nj]), acc[mt][nj]);                     \
                acc[mt][nj] = MFMA(AH1, asbf(bh_[nj] ^ SM), acc[mt][nj]);                \
            }                                                                            \
        }                                                                                \
    }

#define XPART(ts, xv0, xv1)                                                              \
    {                                                                                    \
        bf16x8 XH0 = asbf(xv0), XH1 = asbf(xv1);                                         \
        _Pragma("unroll")                                                                \
        for (int mt = 0; mt < 4; ++mt) {                                                 \
            i32x4 ah = ab[(((4 + (ts)) * 4 + mt) * 64 + lane) * 2];                      \
            bf16x8 AH = asbf(ah);                                                        \
            acc[mt][0] = MFMA(AH, XH0, acc[mt][0]);                                      \
            acc[mt][1] = MFMA(AH, XH1, acc[mt][1]);                                      \
        }                                                                                \
    }

#define XEXTRACT(q0, q1, dstvar)                                                         \
    dstvar = (i32x4){                                                                    \
        (int)permb((unsigned)q0[1], (unsigned)q0[0], sel),                               \
        (int)permb((unsigned)q0[3], (unsigned)q0[2], sel),                               \
        (int)permb((unsigned)q1[1], (unsigned)q1[0], sel),                               \
        (int)permb((unsigned)q1[3], (unsigned)q1[2], sel)};

__global__ __launch_bounds__(256, 3) void k_fuse(const unsigned* __restrict__ XT2,
        const ushort* __restrict__ TFB, const ushort* __restrict__ AFB,
        const float* __restrict__ bias2, float* __restrict__ out) {
    int b = blockIdx.x >> 6, lt = blockIdx.x & 63;
    int w = threadIdx.x >> 6, lane = threadIdx.x & 63;
    int col = lane & 15, kgrp = lane >> 4;
    int lbase = lt * 128 + w * 32;
    int lt0 = lbase >> 4;
    const i32x4* tb = (const i32x4*)TFB;
    const i32x4* ab = (const i32x4*)AFB + (size_t)b * 3072;
    const i32x4* xt4 = (const i32x4*)XT2;

    f32x4 acc[4][2];
    #pragma unroll
    for (int i = 0; i < 4; ++i)
        #pragma unroll
        for (int j = 0; j < 2; ++j) acc[i][j] = (f32x4){0.f, 0.f, 0.f, 0.f};

    int sm = (col & 1) ? (int)0x80008000 : 0;
    i32x4 SM = {sm, sm, sm, sm};
    unsigned sel = (col & 1) ? 0x07060302u : 0x05040100u;

    // XT2 i32x4 index: (stripe*4096 + j)*4 + (kgrp&1)*2, stripe = b*4 + ts*2 + (kgrp>>1)
    size_t i00 = ((size_t)(b * 4 + (kgrp >> 1)) * 4096 + ((lbase + col) >> 1)) * 4 + (kgrp & 1) * 2;
    size_t i01 = i00 + 8 * 4;           // l += 16 -> j += 8
    size_t i10 = i00 + (size_t)2 * 4096 * 4;   // ts=1 -> stripe += 2
    size_t i11 = i10 + 8 * 4;
    i32x4 q000 = xt4[i00], q001 = xt4[i00 + 1];
    i32x4 q010 = xt4[i01], q011 = xt4[i01 + 1];
    i32x4 q100 = xt4[i10], q101 = xt4[i10 + 1];
    i32x4 q110 = xt4[i11], q111 = xt4[i11 + 1];

    TPART(0)
    i32x4 xv00, xv01;
    XEXTRACT(q000, q001, xv00)
    XEXTRACT(q010, q011, xv01)
    XPART(0, xv00, xv01)
    TPART(1)
    i32x4 xv10, xv11;
    XEXTRACT(q100, q101, xv10)
    XEXTRACT(q110, q111, xv11)
    XPART(1, xv10, xv11)

    #pragma unroll
    for (int mt = 0; mt < 4; ++mt) {
        #pragma unroll
        for (int r = 0; r < 4; ++r) {
            int c = mt * 16 + kgrp * 4 + r;
            float bias = bias2[b * 64 + c];
            float* op = out + (size_t)(b * 64 + c) * L_ + lbase + col;
            #pragma unroll
            for (int nj = 0; nj < 2; ++nj) {
                float v = acc[mt][nj][r] + bias;
                op[nj * 16] = v / (1.f + __expf(-v));
            }
        }
    }
}

extern "C" void kernel_launch(void* const* d_in, const int* in_sizes, int n_in,
                              void* d_out, int out_size, void* d_ws, size_t ws_size,
                              hipStream_t stream) {
    const float* x    = (const float*)d_in[0];
    const float* emb  = (const float*)d_in[1];
    const float* wpos = (const float*)d_in[2];
    const float* wneg = (const float*)d_in[3];
    const float* Arp  = (const float*)d_in[4];
    const float* Aip  = (const float*)d_in[5];
    const float* Arn  = (const float*)d_in[6];
    const float* Ain  = (const float*)d_in[7];
    const float* w1   = (const float*)d_in[8];
    const float* b1   = (const float*)d_in[9];
    const float* w2   = (const float*)d_in[10];
    const float* b2   = (const float*)d_in[11];
    const float* lw   = (const float*)d_in[12];
    const float* lb   = (const float*)d_in[13];
    float* out = (float*)d_out;
    float* ws = (float*)d_ws;
    ushort*   TFB  = (ushort*)(ws + OFF_TFB);
    ushort*   TLB  = (ushort*)(ws + OFF_TLB);
    ushort*   AFB  = (ushort*)(ws + OFF_AFB);
    float*    XFRP = ws + OFF_XFRP;
    float*    B2   = ws + OFF_B2;
    float*    PHI  = ws + OFF_PHI;
    float*    GB   = ws + OFF_GB;
    float*    WT   = ws + OFF_WT;
    unsigned* XT2  = (unsigned*)(ws + OFF_XT);

    hipLaunchKernelGGL(k_init,  dim3(4272), dim3(256), 0, stream,
                       TLB, TFB, emb, Arp, Aip, Arn, Ain, PHI, w1, b1, w2, b2, GB,
                       wpos, wneg, WT);
    hipLaunchKernelGGL(k_dft,   dim3(4096), dim3(64),  0, stream, x, TLB, XFRP, XT2);
    hipLaunchKernelGGL(k_mix,   dim3(288),  dim3(256), 0, stream, XFRP, WT, PHI,
                       lw, lb, GB, AFB, B2);
    hipLaunchKernelGGL(k_fuse,  dim3(2048), dim3(256), 0, stream, XT2, TFB, AFB, B2, out);
}

// Round 22
// 66.175 us; speedup vs baseline: 1.0854x; 1.0854x over previous
//
#include <hip/hip_runtime.h>
#include <math.h>

#define L_ 8192
#define EMB_ 256
#define HID_ 64

typedef __attribute__((ext_vector_type(8))) short bf16x8;
typedef __attribute__((ext_vector_type(4))) float f32x4;
typedef __attribute__((ext_vector_type(4))) int i32x4;

// workspace layout (floats)
#define OFF_TFB  0           // ushort[512][2][64][8]  synthesis B-frags, hi only
#define OFF_TLB  262144      // ushort[256][4][64][8]  analysis B-frags, hi only
#define OFF_AFB  524288      // ushort[32][6][4][64][16] A-frags (hi+lo)
#define OFF_XFRP 917504      // float[8][128][2048] per-Kseg DFT partials, transposed
#define OFF_B2   3014656     // float[32*64]
#define OFF_PHI  3016704     // float[32*32*4]
#define OFF_GB   3020800     // float2[32*64]
#define OFF_WT   3024896     // float[2][32][64][64][2] transposed mix weights (2 MB)
#define OFF_XT   3549184     // dword[128][4096][16]: (bf16 x[2j,ch], bf16 x[2j+1,ch]) (33.5 MB)

__device__ inline int pkbf(float a, float b) {
    int r;
    asm volatile("v_cvt_pk_bf16_f32 %0, %1, %2" : "=v"(r) : "v"(a), "v"(b));
    return r;
}
__device__ inline bf16x8 asbf(i32x4 v) { union { i32x4 i; bf16x8 h; } u; u.i = v; return u.h; }
#define MFMA(A,B,C) __builtin_amdgcn_mfma_f32_16x16x32_bf16((A),(B),(C),0,0,0)

__device__ inline ushort f2bf(float v) {
    unsigned b = __float_as_uint(v);
    return (ushort)((b + 0x7FFFu + ((b >> 16) & 1u)) >> 16);
}
__device__ inline float bf2f(ushort h) { return __uint_as_float(((unsigned)h) << 16); }
// hardware trig: input in REVOLUTIONS; arg r/8192 is already reduced
__device__ inline float hwsin(float rev) { float r; asm("v_sin_f32 %0, %1" : "=v"(r) : "v"(rev)); return r; }
__device__ inline float hwcos(float rev) { float r; asm("v_cos_f32 %0, %1" : "=v"(r) : "v"(rev)); return r; }
// byte-select from {hi,lo}: idx 0-3 = lo bytes, 4-7 = hi bytes
__device__ inline unsigned permb(unsigned hi, unsigned lo, unsigned sel) {
    unsigned r;
    asm("v_perm_b32 %0, %1, %2, %3" : "=v"(r) : "v"(hi), "v"(lo), "v"(sel));
    return r;
}

// merged init: trig (0..4095) + phi (4096..4111) + mlp (4112..4143) + W-transpose (4144..4271)
__global__ __launch_bounds__(256) void k_init(ushort* __restrict__ TLB, ushort* __restrict__ TFB,
        const float* __restrict__ emb,
        const float* __restrict__ Arp, const float* __restrict__ Aip,
        const float* __restrict__ Arn, const float* __restrict__ Ain, float* __restrict__ phi,
        const float* __restrict__ w1, const float* __restrict__ b1,
        const float* __restrict__ w2, const float* __restrict__ b2, float* __restrict__ gb,
        const float* __restrict__ wpos, const float* __restrict__ wneg, float* __restrict__ WT) {
    int bid = blockIdx.x;
    if (bid < 4096) {
        int idx = bid * 256 + threadIdx.x;   // 0..1048575
        int f, l; ushort* dst;
        if (idx < 524288) {                  // TLB: [kstep 256][ct 4][lane 64][e 8]
            int u = idx;
            int e = u & 7, lane = (u >> 3) & 63, ct = (u >> 9) & 3, kstep = u >> 11;
            l = kstep * 32 + ((lane >> 4) << 3) + e;
            f = ct * 16 + (lane & 15);
            dst = TLB + u;
        } else {                             // TFB: [lt 512][ts 2][lane 64][e 8]
            int u = idx - 524288;
            int e = u & 7, lane = (u >> 3) & 63, ts = (u >> 9) & 1, lt = u >> 10;
            l = lt * 16 + (lane & 15);
            f = ts * 32 + ((lane >> 4) << 3) + e;
            dst = TFB + u;
        }
        int fr = f & 31; bool sinp = (f & 32) != 0;
        int r = (fr * l) & (L_ - 1);
        float rev = (float)r * (1.0f / (float)L_);
        float v = sinp ? hwsin(rev) : hwcos(rev);
        *dst = f2bf(v);
    } else if (bid < 4112) {
        int tid = (bid - 4096) * 256 + threadIdx.x;   // (b*32+mm)*4+cmp
        int b = tid >> 7;
        int mm = (tid >> 2) & 31;
        int cmp = tid & 3;
        const float* A = (cmp == 0) ? Arp : (cmp == 1) ? Aip : (cmp == 2) ? Arn : Ain;
        const float4* e4 = (const float4*)(emb + b * EMB_);
        const float4* a4 = (const float4*)(A + mm * EMB_);
        float acc = 0.f;
        for (int q = 0; q < EMB_ / 4; ++q) {
            float4 ev = e4[q], av = a4[q];
            acc += ev.x * av.x + ev.y * av.y + ev.z * av.z + ev.w * av.w;
        }
        phi[tid] = acc;
    } else if (bid < 4144) {
        __shared__ float h[HID_];
        int b = bid - 4112, t = threadIdx.x;
        if (t < HID_) {
            const float4* e4 = (const float4*)(emb + b * EMB_);
            const float4* w4 = (const float4*)(w1 + t * EMB_);
            float acc = b1[t];
            for (int q = 0; q < EMB_ / 4; ++q) {
                float4 ev = e4[q], wv = w4[q];
                acc += ev.x * wv.x + ev.y * wv.y + ev.z * wv.z + ev.w * wv.w;
            }
            h[t] = acc / (1.f + expf(-acc));
        }
        __syncthreads();
        if (t < 128) {
            float g = b2[t];
            const float4* h4 = (const float4*)h;
            const float4* w4 = (const float4*)(w2 + t * HID_);
            for (int q = 0; q < HID_ / 4; ++q) {
                float4 hv = h4[q], wv = w4[q];
                g += hv.x * wv.x + hv.y * wv.y + hv.z * wv.z + hv.w * wv.w;
            }
            if (t < 64) gb[(b * 64 + t) * 2 + 0] = 1.f + g;
            else        gb[(b * 64 + (t - 64)) * 2 + 1] = g;
        }
    } else {
        // W transpose: W[i][o][mm][ri] -> WT[side][mm][i][o][ri]
        int t = bid - 4144;              // 0..127
        int side = t >> 6, i = t & 63;
        const float* W = side ? wneg : wpos;
        const float* src = W + (size_t)i * 4096;
        int tid = threadIdx.x;
        #pragma unroll
        for (int j = 0; j < 8; ++j) {
            int u = tid + 256 * j;       // 0..2047 float2 units: mm = u>>6, o = u&63
            int mm = u >> 6, o = u & 63;
            float2 v = *(const float2*)(src + o * 64 + mm * 2);
            *(float2*)(WT + ((size_t)(side * 32 + mm)) * 8192 + i * 128 + o * 2) = v;
        }
    }
}

// single-bf16 MFMA DFT, LDS-staged (coalesced loads/stores).
// grid 1024 = stripe(128: 16 rows) x lseg(8: K=1024); 4 waves split K (256 each, 2 chunks of 128)
__global__ __launch_bounds__(256, 4) void k_dft(const float* __restrict__ x,
        const ushort* __restrict__ TLB, float* __restrict__ xfrp, unsigned* __restrict__ XT2) {
    __shared__ float sP[2][16][132];
    __shared__ unsigned sX[4][16][68];      // per-wave bf16-pair staging, stride 68 (16B-aligned rows)
    int stripe = blockIdx.x >> 3;
    int lseg = blockIdx.x & 7;
    int w = threadIdx.x >> 6;
    int lane = threadIdx.x & 63;
    int r0 = stripe * 16;
    int kb0 = lseg * 1024 + w * 256;

    f32x4 acc[8];
    #pragma unroll
    for (int i = 0; i < 8; ++i) acc[i] = (f32x4){0.f, 0.f, 0.f, 0.f};

    const i32x4* tb = (const i32x4*)TLB;
    int tbase = (kb0 >> 5) * 256 + lane;    // i32x4 index; +256 per kstep, +64 per ct
    const i32x4 SM = {(int)0x80000000, (int)0x80000000, (int)0x80000000, (int)0x80000000};

    int lrow2 = lane >> 5;                  // 0/1: which of the row-pair this lane loads
    int lcol = (lane & 31) * 4;             // column (floats) within 128-chunk
    int jw = (lane & 31) * 2;               // dword j for ds_write
    int frow = lane & 15;                   // fragment row
    int fj = (lane >> 4) * 4;               // fragment dword base (kgrp*4)

    #pragma unroll
    for (int c = 0; c < 2; ++c) {
        int cbase = kb0 + c * 128;
        // coalesced global load: 8 instrs, 2 rows (2 segments) each
        float4 f0 = *(const float4*)(x + (size_t)(r0 + 0  + lrow2) * L_ + cbase + lcol);
        float4 f1 = *(const float4*)(x + (size_t)(r0 + 2  + lrow2) * L_ + cbase + lcol);
        float4 f2 = *(const float4*)(x + (size_t)(r0 + 4  + lrow2) * L_ + cbase + lcol);
        float4 f3 = *(const float4*)(x + (size_t)(r0 + 6  + lrow2) * L_ + cbase + lcol);
        float4 f4 = *(const float4*)(x + (size_t)(r0 + 8  + lrow2) * L_ + cbase + lcol);
        float4 f5 = *(const float4*)(x + (size_t)(r0 + 10 + lrow2) * L_ + cbase + lcol);
        float4 f6 = *(const float4*)(x + (size_t)(r0 + 12 + lrow2) * L_ + cbase + lcol);
        float4 f7 = *(const float4*)(x + (size_t)(r0 + 14 + lrow2) * L_ + cbase + lcol);
        // convert + ds_write (2-way bank = free)
        #define STG(i, fv)                                                   \
            {                                                                \
                unsigned d0 = (unsigned)pkbf(fv.x, fv.y);                    \
                unsigned d1 = (unsigned)pkbf(fv.z, fv.w);                    \
                sX[w][i * 2 + lrow2][jw]     = d0;                           \
                sX[w][i * 2 + lrow2][jw + 1] = d1;                           \
            }
        STG(0, f0) STG(1, f1) STG(2, f2) STG(3, f3)
        STG(4, f4) STG(5, f5) STG(6, f6) STG(7, f7)
        #undef STG
        // MFMA: A-frag = one ds_read_b128 per ks
        #pragma unroll
        for (int ks = 0; ks < 4; ++ks) {
            i32x4 av = *(const i32x4*)&sX[w][frow][ks * 16 + fj];
            bf16x8 AH = asbf(av);
            int ti = tbase + (c * 4 + ks) * 256;
            i32x4 t0 = tb[ti], t1 = tb[ti + 64], t2 = tb[ti + 128], t3 = tb[ti + 192];
            acc[0] = MFMA(AH, asbf(t0), acc[0]); acc[4] = MFMA(AH, asbf(t0 ^ SM), acc[4]);
            acc[1] = MFMA(AH, asbf(t1), acc[1]); acc[5] = MFMA(AH, asbf(t1 ^ SM), acc[5]);
            acc[2] = MFMA(AH, asbf(t2), acc[2]); acc[6] = MFMA(AH, asbf(t2 ^ SM), acc[6]);
            acc[3] = MFMA(AH, asbf(t3), acc[3]); acc[7] = MFMA(AH, asbf(t3 ^ SM), acc[7]);
        }
        // XT2 coalesced store pass: 4 x 1KB dwordx4 stores from transposed LDS read
        {
            unsigned* xtc = XT2 + ((size_t)stripe * 4096 + (cbase >> 1)) * 16;
            int ch4 = (lane & 3) * 4;
            #pragma unroll
            for (int q = 0; q < 4; ++q) {
                int j = q * 16 + (lane >> 2);
                uint4 v;
                v.x = sX[w][ch4 + 0][j];
                v.y = sX[w][ch4 + 1][j];
                v.z = sX[w][ch4 + 2][j];
                v.w = sX[w][ch4 + 3][j];
                *(uint4*)(xtc + (size_t)(q * 256 + lane * 4)) = v;
            }
        }
    }
    int crow = (lane >> 4) << 2;
    int ccol = lane & 15;
    // two-stage reduce: waves 0/1 write, waves 2/3 accumulate
    if (w < 2) {
        #pragma unroll
        for (int ct = 0; ct < 8; ++ct)
            #pragma unroll
            for (int r = 0; r < 4; ++r)
                sP[w][crow + r][ct * 16 + ccol] = acc[ct][r];
    }
    __syncthreads();
    if (w >= 2) {
        #pragma unroll
        for (int ct = 0; ct < 8; ++ct)
            #pragma unroll
            for (int r = 0; r < 4; ++r)
                sP[w - 2][crow + r][ct * 16 + ccol] += acc[ct][r];
    }
    __syncthreads();
    #pragma unroll
    for (int i = 0; i < 8; ++i) {
        int e = threadIdx.x + 256 * i;     // 0..2047
        int rr = e & 15, cc = e >> 4;
        float s = sP[0][rr][cc] + sP[1][rr][cc];
        xfrp[((size_t)(lseg * 128 + cc)) * 2048 + r0 + rr] = s;
    }
}

// mode mixing -> AFB fragments directly.
// blocks 0..255: [mm 32][side 2][bh 4] spectral rows (8 b each); blocks 256..287: Ax fold + bias2
__global__ __launch_bounds__(256) void k_mix(const float* __restrict__ xfrt,
        const float* __restrict__ WT,
        const float* __restrict__ phi, const float* __restrict__ lw,
        const float* __restrict__ lb, const float* __restrict__ gb,
        ushort* __restrict__ afb, float* __restrict__ bias2) {
    int bi = blockIdx.x;
    int tid = threadIdx.x;
    if (bi >= 256) {                 // Ax fold + bias2
        int b = bi - 256;
        ushort* dst = afb + (size_t)b * 24576;
        #pragma unroll
        for (int j = 0; j < 16; ++j) {
            int u = tid + 256 * j;   // 0..4095 : [ks2 2][mt 4][lane 64][e 8]
            int e = u & 7, lane = (u >> 3) & 63, mt = (u >> 9) & 3, ks2 = u >> 11;
            int c = mt * 16 + (lane & 15);
            int kk = ((lane >> 4) << 3) + e;
            float v = lw[c * 64 + ks2 * 32 + kk] * gb[(b * 64 + c) * 2];
            ushort hi = f2bf(v);
            int base = (((4 + ks2) * 4 + mt) * 64 + lane) * 16;
            dst[base + e] = hi;
            dst[base + 8 + e] = f2bf(v - bf2f(hi));
        }
        if (tid < 64) {
            float g1 = gb[(b * 64 + tid) * 2], be = gb[(b * 64 + tid) * 2 + 1];
            bias2[b * 64 + tid] = lb[tid] * g1 + be;
        }
        return;
    }
    __shared__ float sW[64][64][2];     // [i][o][re/im]
    __shared__ float sXr[8][64], sXi[8][64];   // [b_local][i]
    int bh = bi & 3, side = (bi >> 2) & 1, mm = bi >> 3;
    int slot = side ? (31 - mm) : mm;
    int colR = side ? (64 + slot) : mm;
    int colI = side ? (96 + slot) : (32 + mm);

    // stage transposed W tile: coalesced float4
    {
        const float4* wt = (const float4*)(WT + ((size_t)(side * 32 + mm)) * 8192);
        float* sWlin = &sW[0][0][0];
        #pragma unroll
        for (int j = 0; j < 8; ++j) {
            int u = tid + 256 * j;
            *(float4*)&sWlin[u * 4] = wt[u];
        }
    }
    {   // stage 8 b x 64 i sums via float2 per thread; sum 8 slabs
        const float2* pR = (const float2*)(xfrt + (size_t)colR * 2048 + bh * 512);
        const float2* pI = (const float2*)(xfrt + (size_t)colI * 2048 + bh * 512);
        float2 aR = {0, 0}, aI = {0, 0};
        #pragma unroll
        for (int s = 0; s < 8; ++s) {
            float2 vR = pR[(size_t)s * 131072 + tid];
            float2 vI = pI[(size_t)s * 131072 + tid];
            aR.x += vR.x; aR.y += vR.y;
            aI.x += vI.x; aI.y += vI.y;
        }
        if (!side) { aI.x = -aI.x; aI.y = -aI.y; }
        *(float2*)&sXr[tid >> 5][(tid & 31) * 2] = aR;
        *(float2*)&sXi[tid >> 5][(tid & 31) * 2] = aI;
    }
    __syncthreads();

    int o = tid & 63, bg = tid >> 6;
    const float invL = 1.f / (float)L_;
    float fac = (slot == 0) ? invL : 2.f * invL;
    int comp = side ? 2 : 0;
    int e = slot & 7, kgrp = slot >> 3;
    int mt = o >> 4, lane = kgrp * 16 + (o & 15);
    #pragma unroll
    for (int bl = 0; bl < 2; ++bl) {
        int b_local = bg * 2 + bl;
        int b = bh * 8 + b_local;
        float sre = 0.f, sim = 0.f;
        #pragma unroll 16
        for (int i = 0; i < 64; ++i) {
            float wr = sW[i][o][0], wi = sW[i][o][1];
            float xr = sXr[b_local][i], xi = sXi[b_local][i];
            sre += xr * wr - xi * wi;
            sim += xr * wi + xi * wr;
        }
        const float* ph = &phi[(b * 32 + mm) * 4 + (side ? 2 : 0)];
        float phr = ph[0], phim = ph[1];
        float Pre = sre * phr - sim * phim;
        float Pim = sre * phim + sim * phr;
        float a = fac * Pre;
        float bcoef = (slot == 0) ? 0.f : (side ? 2.f * invL * Pim : -2.f * invL * Pim);
        ushort* dst = afb + (size_t)b * 24576;
        ushort hiA = f2bf(a);
        int baseA = ((comp * 4 + mt) * 64 + lane) * 16;
        dst[baseA + e] = hiA;
        dst[baseA + 8 + e] = f2bf(a - bf2f(hiA));
        ushort hiB = f2bf(bcoef);
        int baseB = (((comp + 1) * 4 + mt) * 64 + lane) * 16;
        dst[baseB + e] = hiB;
        dst[baseB + 8 + e] = f2bf(bcoef - bf2f(hiB));
    }
}

// MFMA epilogue GEMM: out[b][c][l] = silu( sum_k A[k][c] * B[k][l] + bias2[c] ),
// B = [T(64); (-1)^l T(64); x[b](64)]; x read from XT2 dword-pairs + v_perm parity extract.
#define TPART(ts)                                                                        \
    {                                                                                    \
        i32x4 bh_[2];                                                                    \
        _Pragma("unroll")                                                                \
        for (int nj = 0; nj < 2; ++nj)                                                   \
            bh_[nj] = tb[((lt0 + nj) * 2 + (ts)) * 64 + lane];                           \
        _Pragma("unroll")                                                                \
        for (int mt = 0; mt < 4; ++mt) {                                                 \
            i32x4 ah0 = ab[(((ts) * 4 + mt) * 64 + lane) * 2];                           \
            i32x4 ah1 = ab[(((2 + (ts)) * 4 + mt) * 64 + lane) * 2];                     \
            bf16x8 AH0 = asbf(ah0), AH1 = asbf(ah1);                                     \
            _Pragma("unroll")                                                            \
            for (int nj = 0; nj < 2; ++nj) {                                             \
                acc[mt][nj] = MFMA(AH0, asbf(bh_[nj]), acc[mt][nj]);                     \
                acc[mt][nj] = MFMA(AH1, asbf(bh_[nj] ^ SM), acc[mt][nj]);                \
            }                                                                            \
        }                                                                                \
    }

#define XPART(ts, xv0, xv1)                                                              \
    {                                                                                    \
        bf16x8 XH0 = asbf(xv0), XH1 = asbf(xv1);                                         \
        _Pragma("unroll")                                                                \
        for (int mt = 0; mt < 4; ++mt) {                                                 \
            i32x4 ah = ab[(((4 + (ts)) * 4 + mt) * 64 + lane) * 2];                      \
            bf16x8 AH = asbf(ah);                                                        \
            acc[mt][0] = MFMA(AH, XH0, acc[mt][0]);                                      \
            acc[mt][1] = MFMA(AH, XH1, acc[mt][1]);                                      \
        }                                                                                \
    }

#define XEXTRACT(q0, q1, dstvar)                                                         \
    dstvar = (i32x4){                                                                    \
        (int)permb((unsigned)q0[1], (unsigned)q0[0], sel),                               \
        (int)permb((unsigned)q0[3], (unsigned)q0[2], sel),                               \
        (int)permb((unsigned)q1[1], (unsigned)q1[0], sel),                               \
        (int)permb((unsigned)q1[3], (unsigned)q1[2], sel)};

__global__ __launch_bounds__(256, 3) void k_fuse(const unsigned* __restrict__ XT2,
        const ushort* __restrict__ TFB, const ushort* __restrict__ AFB,
        const float* __restrict__ bias2, float* __restrict__ out) {
    int b = blockIdx.x >> 6, lt = blockIdx.x & 63;
    int w = threadIdx.x >> 6, lane = threadIdx.x & 63;
    int col = lane & 15, kgrp = lane >> 4;
    int lbase = lt * 128 + w * 32;
    int lt0 = lbase >> 4;
    const i32x4* tb = (const i32x4*)TFB;
    const i32x4* ab = (const i32x4*)AFB + (size_t)b * 3072;
    const i32x4* xt4 = (const i32x4*)XT2;

    f32x4 acc[4][2];
    #pragma unroll
    for (int i = 0; i < 4; ++i)
        #pragma unroll
        for (int j = 0; j < 2; ++j) acc[i][j] = (f32x4){0.f, 0.f, 0.f, 0.f};

    int sm = (col & 1) ? (int)0x80008000 : 0;
    i32x4 SM = {sm, sm, sm, sm};
    unsigned sel = (col & 1) ? 0x07060302u : 0x05040100u;

    // XT2 i32x4 index: (stripe*4096 + j)*4 + (kgrp&1)*2, stripe = b*4 + ts*2 + (kgrp>>1)
    size_t i00 = ((size_t)(b * 4 + (kgrp >> 1)) * 4096 + ((lbase + col) >> 1)) * 4 + (kgrp & 1) * 2;
    size_t i01 = i00 + 8 * 4;           // l += 16 -> j += 8
    size_t i10 = i00 + (size_t)2 * 4096 * 4;   // ts=1 -> stripe += 2
    size_t i11 = i10 + 8 * 4;
    i32x4 q000 = xt4[i00], q001 = xt4[i00 + 1];
    i32x4 q010 = xt4[i01], q011 = xt4[i01 + 1];
    i32x4 q100 = xt4[i10], q101 = xt4[i10 + 1];
    i32x4 q110 = xt4[i11], q111 = xt4[i11 + 1];

    TPART(0)
    i32x4 xv00, xv01;
    XEXTRACT(q000, q001, xv00)
    XEXTRACT(q010, q011, xv01)
    XPART(0, xv00, xv01)
    TPART(1)
    i32x4 xv10, xv11;
    XEXTRACT(q100, q101, xv10)
    XEXTRACT(q110, q111, xv11)
    XPART(1, xv10, xv11)

    #pragma unroll
    for (int mt = 0; mt < 4; ++mt) {
        #pragma unroll
        for (int r = 0; r < 4; ++r) {
            int c = mt * 16 + kgrp * 4 + r;
            float bias = bias2[b * 64 + c];
            float* op = out + (size_t)(b * 64 + c) * L_ + lbase + col;
            #pragma unroll
            for (int nj = 0; nj < 2; ++nj) {
                float v = acc[mt][nj][r] + bias;
                op[nj * 16] = v / (1.f + __expf(-v));
            }
        }
    }
}

extern "C" void kernel_launch(void* const* d_in, const int* in_sizes, int n_in,
                              void* d_out, int out_size, void* d_ws, size_t ws_size,
                              hipStream_t stream) {
    const float* x    = (const float*)d_in[0];
    const float* emb  = (const float*)d_in[1];
    const float* wpos = (const float*)d_in[2];
    const float* wneg = (const float*)d_in[3];
    const float* Arp  = (const float*)d_in[4];
    const float* Aip  = (const float*)d_in[5];
    const float* Arn  = (const float*)d_in[6];
    const float* Ain  = (const float*)d_in[7];
    const float* w1   = (const float*)d_in[8];
    const float* b1   = (const float*)d_in[9];
    const float* w2   = (const float*)d_in[10];
    const float* b2   = (const float*)d_in[11];
    const float* lw   = (const float*)d_in[12];
    const float* lb   = (const float*)d_in[13];
    float* out = (float*)d_out;
    float* ws = (float*)d_ws;
    ushort*   TFB  = (ushort*)(ws + OFF_TFB);
    ushort*   TLB  = (ushort*)(ws + OFF_TLB);
    ushort*   AFB  = (ushort*)(ws + OFF_AFB);
    float*    XFRP = ws + OFF_XFRP;
    float*    B2   = ws + OFF_B2;
    float*    PHI  = ws + OFF_PHI;
    float*    GB   = ws + OFF_GB;
    float*    WT   = ws + OFF_WT;
    unsigned* XT2  = (unsigned*)(ws + OFF_XT);

    hipLaunchKernelGGL(k_init,  dim3(4272), dim3(256), 0, stream,
                       TLB, TFB, emb, Arp, Aip, Arn, Ain, PHI, w1, b1, w2, b2, GB,
                       wpos, wneg, WT);
    hipLaunchKernelGGL(k_dft,   dim3(1024), dim3(256), 0, stream, x, TLB, XFRP, XT2);
    hipLaunchKernelGGL(k_mix,   dim3(288),  dim3(256), 0, stream, XFRP, WT, PHI,
                       lw, lb, GB, AFB, B2);
    hipLaunchKernelGGL(k_fuse,  dim3(2048), dim3(256), 0, stream, XT2, TFB, AFB, B2, out);
}